// Round 6
// baseline (755.986 us; speedup 1.0000x reference)
//
#include <hip/hip_runtime.h>
#include <cstddef>
#include <cstdint>

#define N_SRC 100000
#define N_DST 100000
#define NE    1000000
#define D     128
#define R     3
#define NEG   0.2f
#define N3    (R * N_DST)                 // 300000 flattened (r,dst) rows
#define NE3   (R * NE)                    // 3000000 edges
#define NB3   ((N3 + 255) / 256)          // 1172
#define NROWS_SEM (R * N_DST)
#define NBH   ((N_SRC + 127) / 128)       // 782 blocks per relation
#define NBS   ((NROWS_SEM + 127) / 128)   // 2344
#define NGRP  8                           // dst-range groups (≈ XCDs)
#define GBLK  256                         // blocks per group
#define GRNG  (N3 / NGRP)                 // 37500 rows per group

typedef __attribute__((ext_vector_type(8))) short bf16x8;
typedef __attribute__((ext_vector_type(4))) float f32x4;

__device__ __forceinline__ float b2f(unsigned short u) {
    union { unsigned int i; float f; } v; v.i = ((unsigned int)u) << 16; return v.f;
}
__device__ __forceinline__ unsigned short f2b(float f) {
    union { float f; unsigned int i; } v; v.f = f;
    unsigned int x = v.i;
    return (unsigned short)((x + 0x7fffu + ((x >> 16) & 1u)) >> 16);  // RNE
}
__device__ __forceinline__ float eluf(float x) {
    return x > 0.f ? x : expm1f(x);
}

// v[r][k] = sum_c W[r][k][c] * attn_r[r][c]
__global__ void compute_v(const float* __restrict__ fcW, const float* __restrict__ attn_r,
                          float* __restrict__ v) {
    int r = blockIdx.x;
    int i = threadIdx.x;
    const float* Wrow = fcW + ((size_t)r * D + i) * D;
    const float* ar = attn_r + r * D;
    float s = 0.f;
    #pragma unroll 4
    for (int j = 0; j < D; j++) s += Wrow[j] * ar[j];
    v[r * D + i] = s;
}

// Whi_t/Wlo_t[r][n][k] = split_bf16(W[r][k][n])
__global__ void prep_w(const float* __restrict__ fcW, unsigned short* __restrict__ Wh,
                       unsigned short* __restrict__ Wl) {
    int r = blockIdx.x;
    for (int i = threadIdx.x; i < D * D; i += 256) {
        int n = i >> 7, k = i & 127;
        float x = fcW[(size_t)r * D * D + k * D + n];
        unsigned short hi = f2b(x);
        Wh[(size_t)r * D * D + i] = hi;
        Wl[(size_t)r * D * D + i] = f2b(x - b2f(hi));
    }
}

__global__ void prep_w1(const float* __restrict__ W1, unsigned short* __restrict__ W1t) {
    for (int i = threadIdx.x; i < D * D; i += 256) {
        int n = i >> 7, k = i & 127;
        W1t[i] = f2b(W1[k * D + n]);
    }
}

// er3[r][n] = dst_feat[n] . v[r]  — single pass over dst_feat for all relations
__global__ __launch_bounds__(256) void er_all(const float* __restrict__ dst_feat,
                                              const float* __restrict__ v,
                                              float* __restrict__ er3) {
    int gw = (blockIdx.x * blockDim.x + threadIdx.x) >> 6;
    int lane = threadIdx.x & 63;
    if (gw >= N_DST) return;
    float2 x = ((const float2*)(dst_feat + (size_t)gw * D))[lane];
    #pragma unroll
    for (int r = 0; r < R; r++) {
        float2 vv = ((const float2*)(v + r * D))[lane];
        float s = x.x * vv.x + x.y * vv.y;
        #pragma unroll
        for (int off = 32; off; off >>= 1) s += __shfl_xor(s, off);
        if (lane == 0) er3[(size_t)r * N_DST + gw] = s;
    }
}

// ---------- MFMA GEMM: H = X @ W (bf16x3), fused el, all relations ----------
__global__ __launch_bounds__(512) void gemm_h_all(const float* __restrict__ src_feat,
        const unsigned short* __restrict__ Wh, const unsigned short* __restrict__ Wl,
        const float* __restrict__ attn_l,
        unsigned short* __restrict__ H3, float* __restrict__ el3) {
    __shared__ short Xh[16384], Xl[16384], Bh[16384], Bl[16384];  // 128 KB
    int tid = threadIdx.x;
    int rb = blockIdx.x / NBH, bb = blockIdx.x % NBH;
    const float* X = src_feat + (size_t)rb * N_SRC * D;
    const unsigned short* WhR = Wh + (size_t)rb * D * D;
    const unsigned short* WlR = Wl + (size_t)rb * D * D;
    const float* al = attn_l + rb * D;
    unsigned short* H = H3 + (size_t)rb * N_SRC * D;
    float* el = el3 + (size_t)rb * N_SRC;
    size_t row0 = (size_t)bb * 128;
    #pragma unroll
    for (int p = 0; p < 8; p++) {
        int c = p * 512 + tid;
        int m = c >> 5, c4 = c & 31;
        float4 xv = make_float4(0.f, 0.f, 0.f, 0.f);
        if (row0 + m < N_SRC) xv = ((const float4*)(X + (row0 + m) * D))[c4];
        unsigned short h0 = f2b(xv.x), h1 = f2b(xv.y), h2 = f2b(xv.z), h3 = f2b(xv.w);
        unsigned short l0 = f2b(xv.x - b2f(h0)), l1 = f2b(xv.y - b2f(h1));
        unsigned short l2 = f2b(xv.z - b2f(h2)), l3 = f2b(xv.w - b2f(h3));
        int idx = m * 128 + (((c4 >> 1) ^ (m & 7)) << 3) + ((c4 & 1) << 2);
        *(uint2*)&Xh[idx] = make_uint2((unsigned)h0 | ((unsigned)h1 << 16),
                                       (unsigned)h2 | ((unsigned)h3 << 16));
        *(uint2*)&Xl[idx] = make_uint2((unsigned)l0 | ((unsigned)l1 << 16),
                                       (unsigned)l2 | ((unsigned)l3 << 16));
    }
    #pragma unroll
    for (int p = 0; p < 4; p++) {
        int c = p * 512 + tid;
        int n = c >> 4, cb = c & 15;
        int idx = n * 128 + ((cb ^ (n & 7)) << 3);
        *(uint4*)&Bh[idx] = ((const uint4*)WhR)[c];
        *(uint4*)&Bl[idx] = ((const uint4*)WlR)[c];
    }
    __syncthreads();

    int w = tid >> 6, lane = tid & 63, lr = lane & 15, lg = lane >> 4;
    f32x4 acc[8];
    #pragma unroll
    for (int nt = 0; nt < 8; nt++) acc[nt] = (f32x4){0.f, 0.f, 0.f, 0.f};
    int m = w * 16 + lr;
    #pragma unroll
    for (int kk = 0; kk < 4; kk++) {
        int cb = kk * 4 + lg;
        int ia = m * 128 + ((cb ^ (m & 7)) << 3);
        bf16x8 ah = *(const bf16x8*)&Xh[ia];
        bf16x8 alo = *(const bf16x8*)&Xl[ia];
        #pragma unroll
        for (int nt = 0; nt < 8; nt++) {
            int n = nt * 16 + lr;
            int ib = n * 128 + ((cb ^ (n & 7)) << 3);
            bf16x8 bh = *(const bf16x8*)&Bh[ib];
            bf16x8 bl = *(const bf16x8*)&Bl[ib];
            acc[nt] = __builtin_amdgcn_mfma_f32_16x16x32_bf16(ah, bh, acc[nt], 0, 0, 0);
            acc[nt] = __builtin_amdgcn_mfma_f32_16x16x32_bf16(alo, bh, acc[nt], 0, 0, 0);
            acc[nt] = __builtin_amdgcn_mfma_f32_16x16x32_bf16(ah, bl, acc[nt], 0, 0, 0);
        }
    }
    float alv[8];
    #pragma unroll
    for (int nt = 0; nt < 8; nt++) alv[nt] = al[nt * 16 + lr];
    #pragma unroll
    for (int reg = 0; reg < 4; reg++) {
        size_t row = row0 + w * 16 + lg * 4 + reg;
        bool ok = row < N_SRC;
        float ep = 0.f;
        #pragma unroll
        for (int nt = 0; nt < 8; nt++) {
            float hv = acc[nt][reg];
            ep = fmaf(hv, alv[nt], ep);
            if (ok) H[row * D + nt * 16 + lr] = f2b(hv);
        }
        ep += __shfl_xor(ep, 1); ep += __shfl_xor(ep, 2);
        ep += __shfl_xor(ep, 4); ep += __shfl_xor(ep, 8);
        if (ok && lr == 0) el[row] = ep;
    }
}

// ---------- MFMA GEMM: semantic partials (z is bf16) ----------
__global__ __launch_bounds__(512) void gemm_sem(const unsigned short* __restrict__ Z,
        const unsigned short* __restrict__ W1t, const float* __restrict__ b1,
        const float* __restrict__ w2, float* __restrict__ psem) {
    __shared__ short Xh[16384], Bh[16384];
    __shared__ float redw[8][4];
    int tid = threadIdx.x;
    size_t row0 = (size_t)blockIdx.x * 128;
    #pragma unroll
    for (int p = 0; p < 4; p++) {
        int c = p * 512 + tid;
        int m = c >> 4, cb = c & 15;
        uint4 xv = make_uint4(0u, 0u, 0u, 0u);
        if (row0 + m < NROWS_SEM) xv = ((const uint4*)(Z + (row0 + m) * D))[cb];
        int idx = m * 128 + ((cb ^ (m & 7)) << 3);
        *(uint4*)&Xh[idx] = xv;
    }
    #pragma unroll
    for (int p = 0; p < 4; p++) {
        int c = p * 512 + tid;
        int n = c >> 4, cb = c & 15;
        int idx = n * 128 + ((cb ^ (n & 7)) << 3);
        *(uint4*)&Bh[idx] = ((const uint4*)W1t)[c];
    }
    __syncthreads();

    int w = tid >> 6, lane = tid & 63, lr = lane & 15, lg = lane >> 4;
    f32x4 acc[8];
    #pragma unroll
    for (int nt = 0; nt < 8; nt++) acc[nt] = (f32x4){0.f, 0.f, 0.f, 0.f};
    int m = w * 16 + lr;
    #pragma unroll
    for (int kk = 0; kk < 4; kk++) {
        int cb = kk * 4 + lg;
        int ia = m * 128 + ((cb ^ (m & 7)) << 3);
        bf16x8 ah = *(const bf16x8*)&Xh[ia];
        #pragma unroll
        for (int nt = 0; nt < 8; nt++) {
            int n = nt * 16 + lr;
            int ib = n * 128 + ((cb ^ (n & 7)) << 3);
            bf16x8 bh = *(const bf16x8*)&Bh[ib];
            acc[nt] = __builtin_amdgcn_mfma_f32_16x16x32_bf16(ah, bh, acc[nt], 0, 0, 0);
        }
    }
    float b1v[8], w2v[8];
    #pragma unroll
    for (int nt = 0; nt < 8; nt++) { b1v[nt] = b1[nt * 16 + lr]; w2v[nt] = w2[nt * 16 + lr]; }
    float rs0 = 0.f, rs1 = 0.f, rs2 = 0.f;
    #pragma unroll
    for (int reg = 0; reg < 4; reg++) {
        size_t row = row0 + w * 16 + lg * 4 + reg;
        float sv = 0.f;
        #pragma unroll
        for (int nt = 0; nt < 8; nt++)
            sv += tanhf(acc[nt][reg] + b1v[nt]) * w2v[nt];
        sv += __shfl_xor(sv, 1); sv += __shfl_xor(sv, 2);
        sv += __shfl_xor(sv, 4); sv += __shfl_xor(sv, 8);
        if (lr == 0 && row < NROWS_SEM) {
            int r = (int)(row / N_DST);
            if (r == 0) rs0 += sv; else if (r == 1) rs1 += sv; else rs2 += sv;
        }
    }
    rs0 += __shfl_xor(rs0, 16); rs0 += __shfl_xor(rs0, 32);
    rs1 += __shfl_xor(rs1, 16); rs1 += __shfl_xor(rs1, 32);
    rs2 += __shfl_xor(rs2, 16); rs2 += __shfl_xor(rs2, 32);
    if (lane == 0) { redw[w][0] = rs0; redw[w][1] = rs1; redw[w][2] = rs2; }
    __syncthreads();
    if (tid < 3) {
        float s = 0.f;
        #pragma unroll
        for (int i = 0; i < 8; i++) s += redw[i][tid];
        psem[blockIdx.x * 3 + tid] = s;
    }
}

// ---------- CSR build: XCD-range-filtered count & place ----------
__global__ __launch_bounds__(256) void count_f(const int* __restrict__ ed3,
                                               int* __restrict__ cnt3) {
    int g = blockIdx.x & (NGRP - 1);
    int j = blockIdx.x / NGRP;
    int lo = g * GRNG, hi = lo + GRNG;
    for (int i = j * 256 + threadIdx.x; i < NE3; i += GBLK * 256) {
        int r = (i >= NE) + (i >= 2 * NE);
        int id3 = r * N_DST + ed3[i];
        if (id3 >= lo && id3 < hi) atomicAdd(&cnt3[id3], 1);
    }
}

__global__ void scan_blocks(int* __restrict__ rowptr, int* __restrict__ bsum) {
    __shared__ int tmp[256];
    int i = blockIdx.x * 256 + threadIdx.x;
    int x = (i < N3) ? rowptr[i] : 0;
    tmp[threadIdx.x] = x;
    __syncthreads();
    #pragma unroll
    for (int off = 1; off < 256; off <<= 1) {
        int v = (threadIdx.x >= off) ? tmp[threadIdx.x - off] : 0;
        __syncthreads();
        tmp[threadIdx.x] += v;
        __syncthreads();
    }
    if (i < N3) rowptr[i] = tmp[threadIdx.x] - x;
    if (threadIdx.x == 255) bsum[blockIdx.x] = tmp[255];
}

// global scan of NB3=1172 block sums
__global__ __launch_bounds__(1024) void scan_bsum(int* __restrict__ bsum) {
    __shared__ int sums[1024];
    int t = threadIdx.x;
    int i0 = 2 * t, i1 = 2 * t + 1;
    int a0 = (i0 < NB3) ? bsum[i0] : 0;
    int a1 = (i1 < NB3) ? bsum[i1] : 0;
    sums[t] = a0 + a1;
    __syncthreads();
    #pragma unroll
    for (int off = 1; off < 1024; off <<= 1) {
        int v = (t >= off) ? sums[t - off] : 0;
        __syncthreads();
        sums[t] += v;
        __syncthreads();
    }
    int base = (t > 0) ? sums[t - 1] : 0;
    if (i0 < NB3) bsum[i0] = base;
    if (i1 < NB3) bsum[i1] = base + a0;
}

__global__ void add_offsets(int* __restrict__ rowptr, const int* __restrict__ bsum,
                            int* __restrict__ cursor) {
    int i = blockIdx.x * 256 + threadIdx.x;
    if (i < N3) {
        int vv = rowptr[i] + bsum[blockIdx.x];
        rowptr[i] = vv;
        cursor[i] = vv;
    }
    if (i == 0) rowptr[N3] = NE3;
}

__global__ __launch_bounds__(256) void place_f(const int* __restrict__ es3,
                                               const int* __restrict__ ed3,
                                               int* __restrict__ cursor3,
                                               int* __restrict__ csr_src) {
    int g = blockIdx.x & (NGRP - 1);
    int j = blockIdx.x / NGRP;
    int lo = g * GRNG, hi = lo + GRNG;
    for (int i = j * 256 + threadIdx.x; i < NE3; i += GBLK * 256) {
        int r = (i >= NE) + (i >= 2 * NE);
        int id3 = r * N_DST + ed3[i];
        if (id3 >= lo && id3 < hi) {
            int pos = atomicAdd(&cursor3[id3], 1);
            csr_src[pos] = es3[i];
        }
    }
}

// ---------- per-(r,dst) gather + softmax + elu ----------
// One wave per dst; 4 edge-groups of 16 lanes; each lane covers 8 elements
// (uint4 = 8 bf16) so per-edge scalar overhead (csr/el loads, exp, addr calc,
// loop control) is amortized 4x vs the 64-lane-per-edge layout (round-5:
// VALUBusy 84%, ~84 instrs/edge).
__global__ __launch_bounds__(256) void aggregate_all(const unsigned short* __restrict__ hsrc3,
                                                     const int* __restrict__ csr_src,
                                                     const int* __restrict__ rowptr3,
                                                     const float* __restrict__ el3,
                                                     const float* __restrict__ er3,
                                                     const float* __restrict__ gat_bias,
                                                     unsigned short* __restrict__ z3) {
    int gw3 = (blockIdx.x * blockDim.x + threadIdx.x) >> 6;
    int lane = threadIdx.x & 63;
    if (gw3 >= N3) return;
    int r = gw3 / N_DST;
    int beg = rowptr3[gw3], end = rowptr3[gw3 + 1];
    float erd = er3[gw3];
    const unsigned short* hs = hsrc3 + (size_t)r * N_SRC * D;
    const float* elr = el3 + (size_t)r * N_SRC;
    int lg = lane >> 4;   // edge group 0..3
    int lc = lane & 15;   // element chunk (8 elems each)
    float acc[8] = {};
    float sum = 0.f;
    for (int i = beg + lg; i < end; i += 4) {
        int s = csr_src[i];
        float e = elr[s] + erd;
        e = fmaxf(e, NEG * e);          // leaky_relu
        float x = __expf(e);
        uint4 u = ((const uint4*)(hs + (size_t)s * D))[lc];
        unsigned uu[4] = {u.x, u.y, u.z, u.w};
        #pragma unroll
        for (int q = 0; q < 4; q++) {
            union { unsigned i; float f; } flo, fhi;
            flo.i = uu[q] << 16;
            fhi.i = uu[q] & 0xffff0000u;
            acc[2 * q]     = fmaf(x, flo.f, acc[2 * q]);
            acc[2 * q + 1] = fmaf(x, fhi.f, acc[2 * q + 1]);
        }
        sum += x;
    }
    // reduce across the 4 edge-groups (lane bits 4,5)
    #pragma unroll
    for (int q = 0; q < 8; q++) {
        acc[q] += __shfl_xor(acc[q], 16);
        acc[q] += __shfl_xor(acc[q], 32);
    }
    sum += __shfl_xor(sum, 16);
    sum += __shfl_xor(sum, 32);
    float inv = sum > 0.f ? 1.f / sum : 0.f;
    if (lg == 0) {
        const float* br = gat_bias + r * D + lc * 8;
        unsigned zo[4];
        #pragma unroll
        for (int q = 0; q < 4; q++) {
            unsigned short z0 = f2b(eluf(fmaf(acc[2 * q], inv, br[2 * q])));
            unsigned short z1 = f2b(eluf(fmaf(acc[2 * q + 1], inv, br[2 * q + 1])));
            zo[q] = (unsigned)z0 | ((unsigned)z1 << 16);
        }
        uint4 o; o.x = zo[0]; o.y = zo[1]; o.z = zo[2]; o.w = zo[3];
        ((uint4*)(z3 + (size_t)gw3 * D))[lc] = o;
    }
}

__global__ void finalize_a(const float* __restrict__ psem, float* __restrict__ a_ws,
                           float* __restrict__ out_tail) {
    __shared__ float red[4][4];
    float s0 = 0.f, s1 = 0.f, s2 = 0.f;
    for (int b = threadIdx.x; b < NBS; b += 256) {
        s0 += psem[b * 3]; s1 += psem[b * 3 + 1]; s2 += psem[b * 3 + 2];
    }
    #pragma unroll
    for (int off = 32; off; off >>= 1) {
        s0 += __shfl_xor(s0, off); s1 += __shfl_xor(s1, off); s2 += __shfl_xor(s2, off);
    }
    int w = threadIdx.x >> 6;
    if ((threadIdx.x & 63) == 0) { red[w][0] = s0; red[w][1] = s1; red[w][2] = s2; }
    __syncthreads();
    if (threadIdx.x == 0) {
        float w0 = 0.f, w1 = 0.f, w2v = 0.f;
        #pragma unroll
        for (int i = 0; i < 4; i++) { w0 += red[i][0]; w1 += red[i][1]; w2v += red[i][2]; }
        w0 /= (float)N_DST; w1 /= (float)N_DST; w2v /= (float)N_DST;
        float m = fmaxf(w0, fmaxf(w1, w2v));
        float e0 = expf(w0 - m), e1 = expf(w1 - m), e2 = expf(w2v - m);
        float s = e0 + e1 + e2;
        a_ws[0] = e0 / s; a_ws[1] = e1 / s; a_ws[2] = e2 / s;
        out_tail[0] = e0 / s; out_tail[1] = e1 / s; out_tail[2] = e2 / s;
    }
}

// z_out = sum_r a[r] * z[r]  (z bf16, out fp32), 8 elems/thread
__global__ __launch_bounds__(256) void combine(const unsigned short* __restrict__ z3,
                                               const float* __restrict__ a,
                                               float* __restrict__ out) {
    size_t f = (size_t)blockIdx.x * blockDim.x + threadIdx.x;  // uint4 (8 bf16) index
    if (f >= (size_t)N_DST * D / 8) return;
    float accv[8] = {};
    #pragma unroll
    for (int r = 0; r < R; r++) {
        float ar = a[r];
        uint4 u = ((const uint4*)z3)[(size_t)r * (N_DST * D / 8) + f];
        unsigned int uu[4] = {u.x, u.y, u.z, u.w};
        #pragma unroll
        for (int q = 0; q < 4; q++) {
            accv[2 * q]     = fmaf(ar, b2f((unsigned short)(uu[q] & 0xffff)), accv[2 * q]);
            accv[2 * q + 1] = fmaf(ar, b2f((unsigned short)(uu[q] >> 16)), accv[2 * q + 1]);
        }
    }
    float4* o4 = (float4*)(out + f * 8);
    o4[0] = make_float4(accv[0], accv[1], accv[2], accv[3]);
    o4[1] = make_float4(accv[4], accv[5], accv[6], accv[7]);
}

extern "C" void kernel_launch(void* const* d_in, const int* in_sizes, int n_in,
                              void* d_out, int out_size, void* d_ws, size_t ws_size,
                              hipStream_t stream) {
    const float* dst_feat = (const float*)d_in[0];
    const float* src_feat = (const float*)d_in[1];
    const float* fcW      = (const float*)d_in[2];
    const float* attn_l   = (const float*)d_in[3];
    const float* attn_r   = (const float*)d_in[4];
    const float* gat_bias = (const float*)d_in[5];
    const float* sem_W1   = (const float*)d_in[6];
    const float* sem_b1   = (const float*)d_in[7];
    const float* sem_w2   = (const float*)d_in[8];
    const int* edge_src   = (const int*)d_in[9];
    const int* edge_dst   = (const int*)d_in[10];
    float* out = (float*)d_out;

    char* p = (char*)d_ws;
    auto alloc = [&](size_t bytes) {
        p = (char*)(((uintptr_t)p + 255) & ~(uintptr_t)255);
        char* r = p; p += bytes; return (void*)r;
    };
    unsigned short* z3   = (unsigned short*)alloc((size_t)N3 * D * sizeof(short));
    unsigned short* hsrc3= (unsigned short*)alloc((size_t)R * N_SRC * D * sizeof(short));
    float* el3    = (float*)alloc((size_t)R * N_SRC * sizeof(float));
    float* er3    = (float*)alloc((size_t)R * N_DST * sizeof(float));
    float* v      = (float*)alloc(R * D * sizeof(float));
    float* a      = (float*)alloc(R * sizeof(float));
    float* psem   = (float*)alloc((size_t)NBS * 3 * sizeof(float));
    unsigned short* Whi  = (unsigned short*)alloc((size_t)R * D * D * sizeof(short));
    unsigned short* Wlo  = (unsigned short*)alloc((size_t)R * D * D * sizeof(short));
    unsigned short* W1t  = (unsigned short*)alloc((size_t)D * D * sizeof(short));
    int* rowptr3 = (int*)alloc((size_t)(N3 + 1) * sizeof(int));
    int* cursor3 = (int*)alloc((size_t)N3 * sizeof(int));
    int* bsum    = (int*)alloc(2048 * sizeof(int));
    int* csr_src = (int*)alloc((size_t)NE3 * sizeof(int));

    prep_w<<<R, 256, 0, stream>>>(fcW, Whi, Wlo);
    prep_w1<<<1, 256, 0, stream>>>(sem_W1, W1t);
    compute_v<<<R, D, 0, stream>>>(fcW, attn_r, v);

    // CSR build (all relations, XCD-range-filtered count/place)
    hipMemsetAsync(rowptr3, 0, (size_t)(N3 + 1) * sizeof(int), stream);
    count_f<<<NGRP * GBLK, 256, 0, stream>>>(edge_dst, rowptr3);
    scan_blocks<<<NB3, 256, 0, stream>>>(rowptr3, bsum);
    scan_bsum<<<1, 1024, 0, stream>>>(bsum);
    add_offsets<<<NB3, 256, 0, stream>>>(rowptr3, bsum, cursor3);
    place_f<<<NGRP * GBLK, 256, 0, stream>>>(edge_src, edge_dst, cursor3, csr_src);

    // dense phase (all relations)
    gemm_h_all<<<R * NBH, 512, 0, stream>>>(src_feat, Whi, Wlo, attn_l, hsrc3, el3);
    er_all<<<N_DST / 4, 256, 0, stream>>>(dst_feat, v, er3);

    // gather + softmax + elu -> z (bf16)
    aggregate_all<<<N3 / 4, 256, 0, stream>>>(hsrc3, csr_src, rowptr3, el3, er3,
                                              gat_bias, z3);

    gemm_sem<<<NBS, 512, 0, stream>>>(z3, W1t, sem_b1, sem_w2, psem);
    finalize_a<<<1, 256, 0, stream>>>(psem, a, out + (size_t)N_DST * D);
    combine<<<(N_DST * D / 8 + 255) / 256, 256, 0, stream>>>(z3, a, out);
}

// Round 7
// 703.875 us; speedup vs baseline: 1.0740x; 1.0740x over previous
//
#include <hip/hip_runtime.h>
#include <cstddef>
#include <cstdint>

#define N_SRC 100000
#define N_DST 100000
#define NE    1000000
#define D     128
#define R     3
#define NEG   0.2f
#define N3    (R * N_DST)                 // 300000 flattened (r,dst) rows
#define NE3   (R * NE)                    // 3000000 edges
#define NB3   ((N3 + 255) / 256)          // 1172
#define NROWS_SEM (R * N_DST)
#define NBH64 ((N_SRC + 63) / 64)         // 1563 blocks per relation (64-row tiles)
#define NBS   ((NROWS_SEM + 127) / 128)   // 2344
#define NGRP  8                           // dst-range groups (≈ XCDs)
#define GBLK  256                         // blocks per group
#define GRNG  (N3 / NGRP)                 // 37500 rows per group

typedef __attribute__((ext_vector_type(8))) short bf16x8;
typedef __attribute__((ext_vector_type(4))) float f32x4;

__device__ __forceinline__ float b2f(unsigned short u) {
    union { unsigned int i; float f; } v; v.i = ((unsigned int)u) << 16; return v.f;
}
__device__ __forceinline__ unsigned short f2b(float f) {
    union { float f; unsigned int i; } v; v.f = f;
    unsigned int x = v.i;
    return (unsigned short)((x + 0x7fffu + ((x >> 16) & 1u)) >> 16);  // RNE
}
__device__ __forceinline__ float eluf(float x) {
    return x > 0.f ? x : expm1f(x);
}

// v[r][k] = sum_c W[r][k][c] * attn_r[r][c]
__global__ void compute_v(const float* __restrict__ fcW, const float* __restrict__ attn_r,
                          float* __restrict__ v) {
    int r = blockIdx.x;
    int i = threadIdx.x;
    const float* Wrow = fcW + ((size_t)r * D + i) * D;
    const float* ar = attn_r + r * D;
    float s = 0.f;
    #pragma unroll 4
    for (int j = 0; j < D; j++) s += Wrow[j] * ar[j];
    v[r * D + i] = s;
}

// Wh_t[r][n][k] = bf16(W[r][k][n])  (transposed for MFMA B-frags, single term)
__global__ void prep_w(const float* __restrict__ fcW, unsigned short* __restrict__ Wh) {
    int r = blockIdx.x;
    for (int i = threadIdx.x; i < D * D; i += 256) {
        int n = i >> 7, k = i & 127;
        Wh[(size_t)r * D * D + i] = f2b(fcW[(size_t)r * D * D + k * D + n]);
    }
}

__global__ void prep_w1(const float* __restrict__ W1, unsigned short* __restrict__ W1t) {
    for (int i = threadIdx.x; i < D * D; i += 256) {
        int n = i >> 7, k = i & 127;
        W1t[i] = f2b(W1[k * D + n]);
    }
}

// er3[r][n] = dst_feat[n] . v[r]  — single pass over dst_feat for all relations
__global__ __launch_bounds__(256) void er_all(const float* __restrict__ dst_feat,
                                              const float* __restrict__ v,
                                              float* __restrict__ er3) {
    int gw = (blockIdx.x * blockDim.x + threadIdx.x) >> 6;
    int lane = threadIdx.x & 63;
    if (gw >= N_DST) return;
    float2 x = ((const float2*)(dst_feat + (size_t)gw * D))[lane];
    #pragma unroll
    for (int r = 0; r < R; r++) {
        float2 vv = ((const float2*)(v + r * D))[lane];
        float s = x.x * vv.x + x.y * vv.y;
        #pragma unroll
        for (int off = 32; off; off >>= 1) s += __shfl_xor(s, off);
        if (lane == 0) er3[(size_t)r * N_DST + gw] = s;
    }
}

// ---------- MFMA GEMM: H = X @ W (bf16x2: Xhi*Wh + Xlo*Wh), fused el ----------
// 64-row tiles, 256 threads, LDS = 16+16+32 = 64 KB -> 2 blocks/CU (round-6
// version was 128 KB -> 1 block/CU, no inter-block stage/MFMA overlap).
__global__ __launch_bounds__(256) void gemm_h_all(const float* __restrict__ src_feat,
        const unsigned short* __restrict__ Wh, const float* __restrict__ attn_l,
        unsigned short* __restrict__ H3, float* __restrict__ el3) {
    __shared__ short Xh[64 * 128], Xl[64 * 128];   // 16 KB each
    __shared__ short Bh[128 * 128];                // 32 KB
    int tid = threadIdx.x;
    int rb = blockIdx.x / NBH64, bb = blockIdx.x % NBH64;
    const float* X = src_feat + (size_t)rb * N_SRC * D;
    const unsigned short* WhR = Wh + (size_t)rb * D * D;
    const float* al = attn_l + rb * D;
    unsigned short* H = H3 + (size_t)rb * N_SRC * D;
    float* el = el3 + (size_t)rb * N_SRC;
    size_t row0 = (size_t)bb * 64;
    // stage X (fp32 -> bf16 hi/lo, XOR-swizzled 16B blocks): 64 rows x 32 float4
    #pragma unroll
    for (int p = 0; p < 8; p++) {
        int c = p * 256 + tid;
        int m = c >> 5, c4 = c & 31;
        float4 xv = make_float4(0.f, 0.f, 0.f, 0.f);
        if (row0 + m < N_SRC) xv = ((const float4*)(X + (row0 + m) * D))[c4];
        unsigned short h0 = f2b(xv.x), h1 = f2b(xv.y), h2 = f2b(xv.z), h3 = f2b(xv.w);
        unsigned short l0 = f2b(xv.x - b2f(h0)), l1 = f2b(xv.y - b2f(h1));
        unsigned short l2 = f2b(xv.z - b2f(h2)), l3 = f2b(xv.w - b2f(h3));
        int idx = m * 128 + (((c4 >> 1) ^ (m & 7)) << 3) + ((c4 & 1) << 2);
        *(uint2*)&Xh[idx] = make_uint2((unsigned)h0 | ((unsigned)h1 << 16),
                                       (unsigned)h2 | ((unsigned)h3 << 16));
        *(uint2*)&Xl[idx] = make_uint2((unsigned)l0 | ((unsigned)l1 << 16),
                                       (unsigned)l2 | ((unsigned)l3 << 16));
    }
    // stage W (transposed bf16 in global): 2048 x 16B
    #pragma unroll
    for (int p = 0; p < 8; p++) {
        int c = p * 256 + tid;
        int n = c >> 4, cb = c & 15;
        int idx = n * 128 + ((cb ^ (n & 7)) << 3);
        *(uint4*)&Bh[idx] = ((const uint4*)WhR)[c];
    }
    __syncthreads();

    int w = tid >> 6, lane = tid & 63, lr = lane & 15, lg = lane >> 4;
    f32x4 acc[8];
    #pragma unroll
    for (int nt = 0; nt < 8; nt++) acc[nt] = (f32x4){0.f, 0.f, 0.f, 0.f};
    int m = w * 16 + lr;
    #pragma unroll
    for (int kk = 0; kk < 4; kk++) {
        int cb = kk * 4 + lg;
        int ia = m * 128 + ((cb ^ (m & 7)) << 3);
        bf16x8 ah = *(const bf16x8*)&Xh[ia];
        bf16x8 alo = *(const bf16x8*)&Xl[ia];
        #pragma unroll
        for (int nt = 0; nt < 8; nt++) {
            int n = nt * 16 + lr;
            int ib = n * 128 + ((cb ^ (n & 7)) << 3);
            bf16x8 bh = *(const bf16x8*)&Bh[ib];
            acc[nt] = __builtin_amdgcn_mfma_f32_16x16x32_bf16(ah, bh, acc[nt], 0, 0, 0);
            acc[nt] = __builtin_amdgcn_mfma_f32_16x16x32_bf16(alo, bh, acc[nt], 0, 0, 0);
        }
    }
    // epilogue: store H bf16 + fused el row-dot
    float alv[8];
    #pragma unroll
    for (int nt = 0; nt < 8; nt++) alv[nt] = al[nt * 16 + lr];
    #pragma unroll
    for (int reg = 0; reg < 4; reg++) {
        size_t row = row0 + w * 16 + lg * 4 + reg;
        bool ok = row < N_SRC;
        float ep = 0.f;
        #pragma unroll
        for (int nt = 0; nt < 8; nt++) {
            float hv = acc[nt][reg];
            ep = fmaf(hv, alv[nt], ep);
            if (ok) H[row * D + nt * 16 + lr] = f2b(hv);
        }
        ep += __shfl_xor(ep, 1); ep += __shfl_xor(ep, 2);
        ep += __shfl_xor(ep, 4); ep += __shfl_xor(ep, 8);
        if (ok && lr == 0) el[row] = ep;
    }
}

// ---------- MFMA GEMM: semantic partials (z is bf16) ----------
__global__ __launch_bounds__(512) void gemm_sem(const unsigned short* __restrict__ Z,
        const unsigned short* __restrict__ W1t, const float* __restrict__ b1,
        const float* __restrict__ w2, float* __restrict__ psem) {
    __shared__ short Xh[16384], Bh[16384];
    __shared__ float redw[8][4];
    int tid = threadIdx.x;
    size_t row0 = (size_t)blockIdx.x * 128;
    #pragma unroll
    for (int p = 0; p < 4; p++) {
        int c = p * 512 + tid;
        int m = c >> 4, cb = c & 15;
        uint4 xv = make_uint4(0u, 0u, 0u, 0u);
        if (row0 + m < NROWS_SEM) xv = ((const uint4*)(Z + (row0 + m) * D))[cb];
        int idx = m * 128 + ((cb ^ (m & 7)) << 3);
        *(uint4*)&Xh[idx] = xv;
    }
    #pragma unroll
    for (int p = 0; p < 4; p++) {
        int c = p * 512 + tid;
        int n = c >> 4, cb = c & 15;
        int idx = n * 128 + ((cb ^ (n & 7)) << 3);
        *(uint4*)&Bh[idx] = ((const uint4*)W1t)[c];
    }
    __syncthreads();

    int w = tid >> 6, lane = tid & 63, lr = lane & 15, lg = lane >> 4;
    f32x4 acc[8];
    #pragma unroll
    for (int nt = 0; nt < 8; nt++) acc[nt] = (f32x4){0.f, 0.f, 0.f, 0.f};
    int m = w * 16 + lr;
    #pragma unroll
    for (int kk = 0; kk < 4; kk++) {
        int cb = kk * 4 + lg;
        int ia = m * 128 + ((cb ^ (m & 7)) << 3);
        bf16x8 ah = *(const bf16x8*)&Xh[ia];
        #pragma unroll
        for (int nt = 0; nt < 8; nt++) {
            int n = nt * 16 + lr;
            int ib = n * 128 + ((cb ^ (n & 7)) << 3);
            bf16x8 bh = *(const bf16x8*)&Bh[ib];
            acc[nt] = __builtin_amdgcn_mfma_f32_16x16x32_bf16(ah, bh, acc[nt], 0, 0, 0);
        }
    }
    float b1v[8], w2v[8];
    #pragma unroll
    for (int nt = 0; nt < 8; nt++) { b1v[nt] = b1[nt * 16 + lr]; w2v[nt] = w2[nt * 16 + lr]; }
    float rs0 = 0.f, rs1 = 0.f, rs2 = 0.f;
    #pragma unroll
    for (int reg = 0; reg < 4; reg++) {
        size_t row = row0 + w * 16 + lg * 4 + reg;
        float sv = 0.f;
        #pragma unroll
        for (int nt = 0; nt < 8; nt++)
            sv += tanhf(acc[nt][reg] + b1v[nt]) * w2v[nt];
        sv += __shfl_xor(sv, 1); sv += __shfl_xor(sv, 2);
        sv += __shfl_xor(sv, 4); sv += __shfl_xor(sv, 8);
        if (lr == 0 && row < NROWS_SEM) {
            int r = (int)(row / N_DST);
            if (r == 0) rs0 += sv; else if (r == 1) rs1 += sv; else rs2 += sv;
        }
    }
    rs0 += __shfl_xor(rs0, 16); rs0 += __shfl_xor(rs0, 32);
    rs1 += __shfl_xor(rs1, 16); rs1 += __shfl_xor(rs1, 32);
    rs2 += __shfl_xor(rs2, 16); rs2 += __shfl_xor(rs2, 32);
    if (lane == 0) { redw[w][0] = rs0; redw[w][1] = rs1; redw[w][2] = rs2; }
    __syncthreads();
    if (tid < 3) {
        float s = 0.f;
        #pragma unroll
        for (int i = 0; i < 8; i++) s += redw[i][tid];
        psem[blockIdx.x * 3 + tid] = s;
    }
}

// ---------- CSR build: XCD-range-filtered count & place ----------
__global__ __launch_bounds__(256) void count_f(const int* __restrict__ ed3,
                                               int* __restrict__ cnt3) {
    int g = blockIdx.x & (NGRP - 1);
    int j = blockIdx.x / NGRP;
    int lo = g * GRNG, hi = lo + GRNG;
    for (int i = j * 256 + threadIdx.x; i < NE3; i += GBLK * 256) {
        int r = (i >= NE) + (i >= 2 * NE);
        int id3 = r * N_DST + ed3[i];
        if (id3 >= lo && id3 < hi) atomicAdd(&cnt3[id3], 1);
    }
}

__global__ void scan_blocks(int* __restrict__ rowptr, int* __restrict__ bsum) {
    __shared__ int tmp[256];
    int i = blockIdx.x * 256 + threadIdx.x;
    int x = (i < N3) ? rowptr[i] : 0;
    tmp[threadIdx.x] = x;
    __syncthreads();
    #pragma unroll
    for (int off = 1; off < 256; off <<= 1) {
        int v = (threadIdx.x >= off) ? tmp[threadIdx.x - off] : 0;
        __syncthreads();
        tmp[threadIdx.x] += v;
        __syncthreads();
    }
    if (i < N3) rowptr[i] = tmp[threadIdx.x] - x;
    if (threadIdx.x == 255) bsum[blockIdx.x] = tmp[255];
}

// global scan of NB3=1172 block sums
__global__ __launch_bounds__(1024) void scan_bsum(int* __restrict__ bsum) {
    __shared__ int sums[1024];
    int t = threadIdx.x;
    int i0 = 2 * t, i1 = 2 * t + 1;
    int a0 = (i0 < NB3) ? bsum[i0] : 0;
    int a1 = (i1 < NB3) ? bsum[i1] : 0;
    sums[t] = a0 + a1;
    __syncthreads();
    #pragma unroll
    for (int off = 1; off < 1024; off <<= 1) {
        int v = (t >= off) ? sums[t - off] : 0;
        __syncthreads();
        sums[t] += v;
        __syncthreads();
    }
    int base = (t > 0) ? sums[t - 1] : 0;
    if (i0 < NB3) bsum[i0] = base;
    if (i1 < NB3) bsum[i1] = base + a0;
}

__global__ void add_offsets(int* __restrict__ rowptr, const int* __restrict__ bsum,
                            int* __restrict__ cursor) {
    int i = blockIdx.x * 256 + threadIdx.x;
    if (i < N3) {
        int vv = rowptr[i] + bsum[blockIdx.x];
        rowptr[i] = vv;
        cursor[i] = vv;
    }
    if (i == 0) rowptr[N3] = NE3;
}

__global__ __launch_bounds__(256) void place_f(const int* __restrict__ es3,
                                               const int* __restrict__ ed3,
                                               int* __restrict__ cursor3,
                                               int* __restrict__ csr_src) {
    int g = blockIdx.x & (NGRP - 1);
    int j = blockIdx.x / NGRP;
    int lo = g * GRNG, hi = lo + GRNG;
    for (int i = j * 256 + threadIdx.x; i < NE3; i += GBLK * 256) {
        int r = (i >= NE) + (i >= 2 * NE);
        int id3 = r * N_DST + ed3[i];
        if (id3 >= lo && id3 < hi) {
            int pos = atomicAdd(&cursor3[id3], 1);
            csr_src[pos] = es3[i];
        }
    }
}

// ---------- per-(r,dst) gather + softmax + elu (round-5 structure, measured
// fastest; aggregate is random-granule-BW floored at ~3 TB/s, not VALU) ----------
__global__ __launch_bounds__(256) void aggregate_all(const unsigned short* __restrict__ hsrc3,
                                                     const int* __restrict__ csr_src,
                                                     const int* __restrict__ rowptr3,
                                                     const float* __restrict__ el3,
                                                     const float* __restrict__ er3,
                                                     const float* __restrict__ gat_bias,
                                                     unsigned short* __restrict__ z3) {
    int gw3 = (blockIdx.x * blockDim.x + threadIdx.x) >> 6;
    int lane = threadIdx.x & 63;
    if (gw3 >= N3) return;
    int r = gw3 / N_DST;
    int beg = rowptr3[gw3], end = rowptr3[gw3 + 1];
    float erd = er3[gw3];
    const unsigned short* hs = hsrc3 + (size_t)r * N_SRC * D;
    const float* elr = el3 + (size_t)r * N_SRC;
    float2 acc = make_float2(0.f, 0.f);
    float sum = 0.f;
    int i = beg;
    for (; i + 2 <= end; i += 2) {
        int s0 = csr_src[i], s1 = csr_src[i + 1];
        float e0 = elr[s0] + erd, e1 = elr[s1] + erd;
        e0 = fmaxf(e0, NEG * e0);
        e1 = fmaxf(e1, NEG * e1);
        float x0 = __expf(e0), x1 = __expf(e1);
        ushort2 u0 = ((const ushort2*)(hs + (size_t)s0 * D))[lane];
        ushort2 u1 = ((const ushort2*)(hs + (size_t)s1 * D))[lane];
        acc.x = fmaf(x0, b2f(u0.x), acc.x);
        acc.y = fmaf(x0, b2f(u0.y), acc.y);
        acc.x = fmaf(x1, b2f(u1.x), acc.x);
        acc.y = fmaf(x1, b2f(u1.y), acc.y);
        sum += x0 + x1;
    }
    if (i < end) {
        int s0 = csr_src[i];
        float e0 = elr[s0] + erd;
        e0 = fmaxf(e0, NEG * e0);
        float x0 = __expf(e0);
        ushort2 u0 = ((const ushort2*)(hs + (size_t)s0 * D))[lane];
        acc.x = fmaf(x0, b2f(u0.x), acc.x);
        acc.y = fmaf(x0, b2f(u0.y), acc.y);
        sum += x0;
    }
    float inv = sum > 0.f ? 1.f / sum : 0.f;
    float2 b = ((const float2*)(gat_bias + r * D))[lane];
    ushort2 zu;
    zu.x = f2b(eluf(fmaf(acc.x, inv, b.x)));
    zu.y = f2b(eluf(fmaf(acc.y, inv, b.y)));
    ((ushort2*)(z3 + (size_t)gw3 * D))[lane] = zu;
}

__global__ void finalize_a(const float* __restrict__ psem, float* __restrict__ a_ws,
                           float* __restrict__ out_tail) {
    __shared__ float red[4][4];
    float s0 = 0.f, s1 = 0.f, s2 = 0.f;
    for (int b = threadIdx.x; b < NBS; b += 256) {
        s0 += psem[b * 3]; s1 += psem[b * 3 + 1]; s2 += psem[b * 3 + 2];
    }
    #pragma unroll
    for (int off = 32; off; off >>= 1) {
        s0 += __shfl_xor(s0, off); s1 += __shfl_xor(s1, off); s2 += __shfl_xor(s2, off);
    }
    int w = threadIdx.x >> 6;
    if ((threadIdx.x & 63) == 0) { red[w][0] = s0; red[w][1] = s1; red[w][2] = s2; }
    __syncthreads();
    if (threadIdx.x == 0) {
        float w0 = 0.f, w1 = 0.f, w2v = 0.f;
        #pragma unroll
        for (int i = 0; i < 4; i++) { w0 += red[i][0]; w1 += red[i][1]; w2v += red[i][2]; }
        w0 /= (float)N_DST; w1 /= (float)N_DST; w2v /= (float)N_DST;
        float m = fmaxf(w0, fmaxf(w1, w2v));
        float e0 = expf(w0 - m), e1 = expf(w1 - m), e2 = expf(w2v - m);
        float s = e0 + e1 + e2;
        a_ws[0] = e0 / s; a_ws[1] = e1 / s; a_ws[2] = e2 / s;
        out_tail[0] = e0 / s; out_tail[1] = e1 / s; out_tail[2] = e2 / s;
    }
}

// z_out = sum_r a[r] * z[r]  (z bf16, out fp32), 8 elems/thread
__global__ __launch_bounds__(256) void combine(const unsigned short* __restrict__ z3,
                                               const float* __restrict__ a,
                                               float* __restrict__ out) {
    size_t f = (size_t)blockIdx.x * blockDim.x + threadIdx.x;  // uint4 (8 bf16) index
    if (f >= (size_t)N_DST * D / 8) return;
    float accv[8] = {};
    #pragma unroll
    for (int r = 0; r < R; r++) {
        float ar = a[r];
        uint4 u = ((const uint4*)z3)[(size_t)r * (N_DST * D / 8) + f];
        unsigned int uu[4] = {u.x, u.y, u.z, u.w};
        #pragma unroll
        for (int q = 0; q < 4; q++) {
            accv[2 * q]     = fmaf(ar, b2f((unsigned short)(uu[q] & 0xffff)), accv[2 * q]);
            accv[2 * q + 1] = fmaf(ar, b2f((unsigned short)(uu[q] >> 16)), accv[2 * q + 1]);
        }
    }
    float4* o4 = (float4*)(out + f * 8);
    o4[0] = make_float4(accv[0], accv[1], accv[2], accv[3]);
    o4[1] = make_float4(accv[4], accv[5], accv[6], accv[7]);
}

extern "C" void kernel_launch(void* const* d_in, const int* in_sizes, int n_in,
                              void* d_out, int out_size, void* d_ws, size_t ws_size,
                              hipStream_t stream) {
    const float* dst_feat = (const float*)d_in[0];
    const float* src_feat = (const float*)d_in[1];
    const float* fcW      = (const float*)d_in[2];
    const float* attn_l   = (const float*)d_in[3];
    const float* attn_r   = (const float*)d_in[4];
    const float* gat_bias = (const float*)d_in[5];
    const float* sem_W1   = (const float*)d_in[6];
    const float* sem_b1   = (const float*)d_in[7];
    const float* sem_w2   = (const float*)d_in[8];
    const int* edge_src   = (const int*)d_in[9];
    const int* edge_dst   = (const int*)d_in[10];
    float* out = (float*)d_out;

    char* p = (char*)d_ws;
    auto alloc = [&](size_t bytes) {
        p = (char*)(((uintptr_t)p + 255) & ~(uintptr_t)255);
        char* r = p; p += bytes; return (void*)r;
    };
    unsigned short* z3   = (unsigned short*)alloc((size_t)N3 * D * sizeof(short));
    unsigned short* hsrc3= (unsigned short*)alloc((size_t)R * N_SRC * D * sizeof(short));
    float* el3    = (float*)alloc((size_t)R * N_SRC * sizeof(float));
    float* er3    = (float*)alloc((size_t)R * N_DST * sizeof(float));
    float* v      = (float*)alloc(R * D * sizeof(float));
    float* a      = (float*)alloc(R * sizeof(float));
    float* psem   = (float*)alloc((size_t)NBS * 3 * sizeof(float));
    unsigned short* Whi  = (unsigned short*)alloc((size_t)R * D * D * sizeof(short));
    unsigned short* W1t  = (unsigned short*)alloc((size_t)D * D * sizeof(short));
    int* rowptr3 = (int*)alloc((size_t)(N3 + 1) * sizeof(int));
    int* cursor3 = (int*)alloc((size_t)N3 * sizeof(int));
    int* bsum    = (int*)alloc(2048 * sizeof(int));
    int* csr_src = (int*)alloc((size_t)NE3 * sizeof(int));

    prep_w<<<R, 256, 0, stream>>>(fcW, Whi);
    prep_w1<<<1, 256, 0, stream>>>(sem_W1, W1t);
    compute_v<<<R, D, 0, stream>>>(fcW, attn_r, v);

    // CSR build (all relations, XCD-range-filtered count/place)
    hipMemsetAsync(rowptr3, 0, (size_t)(N3 + 1) * sizeof(int), stream);
    count_f<<<NGRP * GBLK, 256, 0, stream>>>(edge_dst, rowptr3);
    scan_blocks<<<NB3, 256, 0, stream>>>(rowptr3, bsum);
    scan_bsum<<<1, 1024, 0, stream>>>(bsum);
    add_offsets<<<NB3, 256, 0, stream>>>(rowptr3, bsum, cursor3);
    place_f<<<NGRP * GBLK, 256, 0, stream>>>(edge_src, edge_dst, cursor3, csr_src);

    // dense phase (all relations)
    gemm_h_all<<<R * NBH64, 256, 0, stream>>>(src_feat, Whi, attn_l, hsrc3, el3);
    er_all<<<N_DST / 4, 256, 0, stream>>>(dst_feat, v, er3);

    // gather + softmax + elu -> z (bf16)
    aggregate_all<<<N3 / 4, 256, 0, stream>>>(hsrc3, csr_src, rowptr3, el3, er3,
                                              gat_bias, z3);

    gemm_sem<<<NBS, 512, 0, stream>>>(z3, W1t, sem_b1, sem_w2, psem);
    finalize_a<<<1, 256, 0, stream>>>(psem, a, out + (size_t)N_DST * D);
    combine<<<(N_DST * D / 8 + 255) / 256, 256, 0, stream>>>(z3, a, out);
}